// Round 3
// baseline (345.250 us; speedup 1.0000x reference)
//
#include <hip/hip_runtime.h>
#include <stdint.h>

// ---------------------------------------------------------------------------
// 5-layer LSTM (H=4, IN=1, B=1024, T=2048) -> final hidden state of top layer.
//
// Latency-bound serial recurrence; design = layer-pipelined wavefront:
//  - block = 4 batch elements, 5 waves (wave l == layer l), 256 blocks (1/CU).
//  - lane q (of 16 per element): hidden j=q>>2, gate type gt=q&3
//    (weight row r = gt*4 + j, PyTorch gate order i,f,g,o).
//  - cross-lane data movement is DPP only:
//      quad_perm 0x00/0x55/0xAA/0xFF : gather i/f/g/o of own hidden unit
//      row_ror:4/8/12 (0x124/8/C)    : lane i reads lane (i-N)&15, i.e.
//                                      delivers h_{(j-m)&3}; weight columns
//                                      pre-rotated k=(j-m)&3 to match.
//  - layers hand off h in CHUNK=16 timestep chunks via LDS ping-pong,
//    one __syncthreads per phase; phase p -> wave l works chunk p-l.
//    Handoff buffer has one slot per lane (redundant h per quad) so both
//    the write and the read are unconditional and conflict-free.
//  - per-chunk input contributions gx[] precomputed up front (off the
//    serial critical path).
//  - weights pre-scaled by -log2e (sigmoid rows) / -2log2e (tanh row):
//    activation = 1 v_exp_f32 + 1 v_rcp_f32.
//    sigma(a) = 1/(1+2^ahat), tanh(a) = (2-A)/A, A = 1+2^ahat, ahat<=126.
// ---------------------------------------------------------------------------

#define T_LEN   2048
#define NLAYER  5
#define CHUNK   16
#define NCHUNK  (T_LEN / CHUNK)        // 128
#define NPHASE  (NCHUNK + NLAYER - 1)  // 132

template <int CTRL>
__device__ __forceinline__ float dppmov(float x) {
  int v = __builtin_amdgcn_mov_dpp(__float_as_int(x), CTRL, 0xF, 0xF, true);
  return __int_as_float(v);
}

__global__ void __launch_bounds__(64 * NLAYER, 1) lstm_pipe(
    const float* __restrict__ x,         // [1024][2048][1]
    const float* __restrict__ w_ih0,     // [16][1]
    const float* __restrict__ w_ih_rest, // [4][16][4]
    const float* __restrict__ w_hh,      // [5][16][4]
    const float* __restrict__ b_ih,      // [5][16]
    const float* __restrict__ b_hh,      // [5][16]
    float* __restrict__ out)             // [1024][4]
{
  const int tid  = threadIdx.x;
  const int l    = tid >> 6;        // wave id == layer
  const int lane = tid & 63;
  const int q    = lane & 15;       // lane within element group (DPP row)
  const int el   = lane >> 4;       // element within block (0..3)
  const int e    = blockIdx.x * 4 + el;
  const int gt   = q & 3;           // 0=i 1=f 2=g 3=o
  const int j    = q >> 2;          // hidden unit index
  const int r    = gt * 4 + j;      // row in 4H weight matrices

  const float LOG2E = 1.4426950408889634f;
  const float s = (gt == 2) ? (-2.0f * LOG2E) : (-LOG2E);

  // ---- preload weights, columns rotated as k=(j-m)&3 (matches row_ror),
  //      pre-scaled by s ----
  float whh[4];
  float wih[4] = {0.f, 0.f, 0.f, 0.f};
  #pragma unroll
  for (int m = 0; m < 4; ++m) {
    const int k = (j - m) & 3;
    whh[m] = w_hh[l * 64 + r * 4 + k] * s;
  }
  if (l > 0) {
    #pragma unroll
    for (int m = 0; m < 4; ++m) {
      const int k = (j - m) & 3;
      wih[m] = w_ih_rest[(l - 1) * 64 + r * 4 + k] * s;
    }
  }
  float wx = 0.f;
  if (l == 0) wx = w_ih0[r] * s;
  const float bias = (b_ih[l * 16 + r] + b_hh[l * 16 + r]) * s;

  // ---- recurrent state: rotated h quadruple + replicated c ----
  float hr0 = 0.f, hr1 = 0.f, hr2 = 0.f, hr3 = 0.f;
  float c = 0.f;

  // layer-boundary ping-pong chunks: [boundary][parity][tc][el][q] (32 KiB)
  __shared__ float buf[NLAYER - 1][2][CHUNK][4][16];

  float gx[CHUNK];

  for (int p = 0; p < NPHASE; ++p) {
    const int n = p - l;                 // chunk index for this wave
    if (n >= 0 && n < NCHUNK) {
      const int par = n & 1;
      const int t0  = n * CHUNK;

      // ---- precompute input contribution for the whole chunk (off the
      //      serial critical path) ----
      if (l == 0) {
        #pragma unroll
        for (int tc = 0; tc < CHUNK; ++tc)
          gx[tc] = fmaf(wx, x[e * T_LEN + t0 + tc], bias);
      } else {
        #pragma unroll
        for (int tc = 0; tc < CHUNK; ++tc) {
          const float a0 = buf[l - 1][par][tc][el][q];  // h^{l-1}_{j}
          const float a1 = dppmov<0x124>(a0);           // h^{l-1}_{(j-1)&3}
          const float a2 = dppmov<0x128>(a0);           // h^{l-1}_{(j-2)&3}
          const float a3 = dppmov<0x12C>(a0);           // h^{l-1}_{(j-3)&3}
          float acc = bias;
          acc = fmaf(wih[0], a0, acc);
          acc = fmaf(wih[1], a1, acc);
          acc = fmaf(wih[2], a2, acc);
          acc = fmaf(wih[3], a3, acc);
          gx[tc] = acc;
        }
      }

      #pragma unroll
      for (int tc = 0; tc < CHUNK; ++tc) {
        // ---- recurrent pre-activation (3-deep fma tree) ----
        float t01 = fmaf(whh[0], hr0, gx[tc]);
        t01 = fmaf(whh[1], hr1, t01);
        float t23 = whh[2] * hr2;
        t23 = fmaf(whh[3], hr3, t23);
        float acc = t01 + t23;

        // ---- activation: sigma = R, tanh = (2-A)*R ----
        acc = fminf(acc, 126.f);                  // avoid inf*0 NaN (tanh lanes)
        const float E = __builtin_amdgcn_exp2f(acc);
        const float A = 1.f + E;
        const float R = __builtin_amdgcn_rcpf(A);
        const float act = (gt == 2) ? (2.f - A) * R : R;

        // ---- gather i,f,g,o of own hidden unit (quad_perm) ----
        const float iv = dppmov<0x00>(act);
        const float fv = dppmov<0x55>(act);
        const float gv = dppmov<0xAA>(act);
        const float ov = dppmov<0xFF>(act);

        // ---- cell + hidden update (every lane of quad j redundantly) ----
        c = fmaf(fv, c, iv * gv);
        const float ct = fminf(c * (-2.f * LOG2E), 126.f);
        const float E2 = __builtin_amdgcn_exp2f(ct);
        const float A2 = 1.f + E2;
        const float R2 = __builtin_amdgcn_rcpf(A2);
        const float h  = ov * ((2.f - A2) * R2);  // o * tanh(c)

        // ---- rotated h quadruple for next step: hr_m = h_{(j-m)&3} ----
        hr0 = h;
        hr1 = dppmov<0x124>(h);
        hr2 = dppmov<0x128>(h);
        hr3 = dppmov<0x12C>(h);

        // ---- publish (unconditional, one slot per lane, conflict-free) ----
        if (l < NLAYER - 1) buf[l][par][tc][el][q] = h;
      }

      // ---- final output: hr0 == h at t = T_LEN-1 ----
      if (l == NLAYER - 1 && n == NCHUNK - 1 && gt == 0) out[e * 4 + j] = hr0;
    }
    __syncthreads();   // all 5 waves, every phase (uniform)
  }
}

extern "C" void kernel_launch(void* const* d_in, const int* in_sizes, int n_in,
                              void* d_out, int out_size, void* d_ws, size_t ws_size,
                              hipStream_t stream) {
  const float* x     = (const float*)d_in[0];
  const float* wih0  = (const float*)d_in[1];
  const float* wrest = (const float*)d_in[2];
  const float* whh   = (const float*)d_in[3];
  const float* bih   = (const float*)d_in[4];
  const float* bhh   = (const float*)d_in[5];
  float* out = (float*)d_out;

  dim3 grid(256);            // 1024 elements / 4 per block
  dim3 block(64 * NLAYER);   // 5 waves: one per layer
  lstm_pipe<<<grid, block, 0, stream>>>(x, wih0, wrest, whh, bih, bhh, out);
}

// Round 6
// 299.890 us; speedup vs baseline: 1.1513x; 1.1513x over previous
//
#include <hip/hip_runtime.h>
#include <stdint.h>

// ---------------------------------------------------------------------------
// 5-layer LSTM (H=4, IN=1, B=1024, T=2048) -> final hidden state of top layer.
//
// Latency-bound serial recurrence; design = layer-pipelined wavefront:
//  - block = 4 batch elements, 5 waves (wave l == layer l), 256 blocks (1/CU).
//  - lane q (of 16 per element): hidden j=q>>2, gate type gt=q&3
//    (weight row r = gt*4 + j, PyTorch gate order i,f,g,o).
//  - cross-lane data movement is DPP only:
//      quad_perm 0x00/0x55/0xAA/0xFF : gather i/f/g/o of own hidden unit
//      row_ror:4/8/12 (0x124/8/C)    : lane i reads lane (i-N)&15 ->
//                                      delivers h_{(j-m)&3}; weight columns
//                                      pre-rotated k=(j-m)&3 to match.
//  - layers hand off h in CHUNK=32 timestep chunks via LDS ping-pong,
//    one __syncthreads per phase; phase p -> wave l works chunk p-l.
//  - chain trims vs the 297us round-3 baseline:
//      * act = fma(k1, R, k0) per-lane consts (tanh = 2*sigmoid(2a)-1)
//      * h  = fma(2*ov, R2, -ov)  (2ov/-ov computed off-chain)
//      * NO clamps needed: fma forms give exact limits at E=0/inf (no inf*0)
//      * wave-0 prefetches next x-chunk (cold-HBM latency off pipeline rate)
//      * CHUNK 32 halves per-phase barrier + LDS-head overhead
//      * serial loop duplicated store/no-store so the wave-uniform
//        "am I a producer" test is fully hoisted off the critical loop
//      * s_setprio(1) around the serial step loop (role-split arbitration on
//        the SIMD hosting 2 of the 5 waves).
//  - weights pre-scaled by -log2e (sigmoid rows) / -2log2e (tanh row):
//    gate activation = 1 v_exp_f32 + 1 v_rcp_f32 + 1 fma.
// ---------------------------------------------------------------------------

#define T_LEN   2048
#define NLAYER  5
#define CHUNK   32
#define NCHUNK  (T_LEN / CHUNK)        // 64
#define NPHASE  (NCHUNK + NLAYER - 1)  // 68

template <int CTRL>
__device__ __forceinline__ float dppmov(float x) {
  int v = __builtin_amdgcn_mov_dpp(__float_as_int(x), CTRL, 0xF, 0xF, true);
  return __int_as_float(v);
}

// One LSTM step on the serial critical path. Updates (hr0..hr3, c) in place.
// STORE: publish h to the layer-boundary LDS slot.
template <bool STORE>
__device__ __forceinline__ void lstm_step(
    float gxv, const float* whh, float k1, float k0,
    float& hr0, float& hr1, float& hr2, float& hr3, float& c,
    float* __restrict__ slot)          // &buf[l][par][tc][el][q] when STORE
{
  const float LOG2E = 1.4426950408889634f;

  // ---- recurrent pre-activation (tree) ----
  float t01 = fmaf(whh[0], hr0, gxv);
  t01 = fmaf(whh[1], hr1, t01);
  float t23 = whh[2] * hr2;
  t23 = fmaf(whh[3], hr3, t23);
  const float acc = t01 + t23;

  // ---- activation: R = 1/(1+2^acc); act = k1*R + k0 ----
  // (sigmoid lanes: R; tanh lane: 2R-1. Exact limits at E=0/inf.)
  const float E = __builtin_amdgcn_exp2f(acc);
  const float A = 1.f + E;
  const float R = __builtin_amdgcn_rcpf(A);
  const float act = fmaf(k1, R, k0);

  // ---- gather i,f,g,o of own hidden unit (quad_perm) ----
  const float iv = dppmov<0x00>(act);
  const float fv = dppmov<0x55>(act);
  const float gv = dppmov<0xAA>(act);
  const float ov = dppmov<0xFF>(act);
  const float ov2 = ov + ov;     // off-chain
  const float ovm = -ov;         // off-chain

  // ---- cell + hidden: h = ov * tanh(c) = fma(2ov, R2, -ov) ----
  c = fmaf(fv, c, iv * gv);
  const float ct = c * (-2.0f * LOG2E);
  const float E2 = __builtin_amdgcn_exp2f(ct);
  const float A2 = 1.f + E2;
  const float R2 = __builtin_amdgcn_rcpf(A2);
  const float h  = fmaf(ov2, R2, ovm);

  // ---- rotated h quadruple for next step: hr_m = h_{(j-m)&3} ----
  hr0 = h;
  hr1 = dppmov<0x124>(h);
  hr2 = dppmov<0x128>(h);
  hr3 = dppmov<0x12C>(h);

  if (STORE) *slot = h;   // unconditional per-lane slot, conflict-free
}

__global__ void __launch_bounds__(64 * NLAYER, 1) lstm_pipe(
    const float* __restrict__ x,         // [1024][2048][1]
    const float* __restrict__ w_ih0,     // [16][1]
    const float* __restrict__ w_ih_rest, // [4][16][4]
    const float* __restrict__ w_hh,      // [5][16][4]
    const float* __restrict__ b_ih,      // [5][16]
    const float* __restrict__ b_hh,      // [5][16]
    float* __restrict__ out)             // [1024][4]
{
  const int tid  = threadIdx.x;
  const int l    = tid >> 6;        // wave id == layer
  const int lane = tid & 63;
  const int q    = lane & 15;       // lane within element group (DPP row)
  const int el   = lane >> 4;       // element within block (0..3)
  const int e    = blockIdx.x * 4 + el;
  const int gt   = q & 3;           // 0=i 1=f 2=g 3=o
  const int j    = q >> 2;          // hidden unit index
  const int r    = gt * 4 + j;      // row in 4H weight matrices

  const float LOG2E = 1.4426950408889634f;
  const float s  = (gt == 2) ? (-2.0f * LOG2E) : (-LOG2E);
  const float k1 = (gt == 2) ? 2.0f : 1.0f;   // act = fma(k1, R, k0)
  const float k0 = (gt == 2) ? -1.0f : 0.0f;

  // ---- preload weights, columns rotated k=(j-m)&3 (matches row_ror), *s ----
  float whh[4];
  float wih[4] = {0.f, 0.f, 0.f, 0.f};
  #pragma unroll
  for (int m = 0; m < 4; ++m) {
    const int k = (j - m) & 3;
    whh[m] = w_hh[l * 64 + r * 4 + k] * s;
  }
  if (l > 0) {
    #pragma unroll
    for (int m = 0; m < 4; ++m) {
      const int k = (j - m) & 3;
      wih[m] = w_ih_rest[(l - 1) * 64 + r * 4 + k] * s;
    }
  }
  float wx = 0.f;
  if (l == 0) wx = w_ih0[r] * s;
  const float bias = (b_ih[l * 16 + r] + b_hh[l * 16 + r]) * s;

  // ---- recurrent state: rotated h quadruple + replicated c ----
  float hr0 = 0.f, hr1 = 0.f, hr2 = 0.f, hr3 = 0.f;
  float c = 0.f;

  // layer-boundary ping-pong chunks: [boundary][parity][tc][el][q] (64 KiB)
  __shared__ float buf[NLAYER - 1][2][CHUNK][4][16];

  float gx[CHUNK];
  float xcur[CHUNK];   // wave-0 x prefetch buffer (holds chunk n at phase n)

  if (l == 0) {
    #pragma unroll
    for (int tc = 0; tc < CHUNK; ++tc) xcur[tc] = x[e * T_LEN + tc];
  }

  for (int p = 0; p < NPHASE; ++p) {
    const int n = p - l;                 // chunk index for this wave
    if (n >= 0 && n < NCHUNK) {
      const int par = n & 1;

      // ---- input contribution for the whole chunk (off the serial path) ----
      if (l == 0) {
        #pragma unroll
        for (int tc = 0; tc < CHUNK; ++tc)
          gx[tc] = fmaf(wx, xcur[tc], bias);
        // prefetch next chunk (WAR on xcur orders after the fmas above;
        // loads fly during the step loop below)
        if (n + 1 < NCHUNK) {
          #pragma unroll
          for (int tc = 0; tc < CHUNK; ++tc)
            xcur[tc] = x[e * T_LEN + (n + 1) * CHUNK + tc];
        }
      } else {
        #pragma unroll
        for (int tc = 0; tc < CHUNK; ++tc) {
          const float a0 = buf[l - 1][par][tc][el][q];  // h^{l-1}_{j}
          const float a1 = dppmov<0x124>(a0);           // h^{l-1}_{(j-1)&3}
          const float a2 = dppmov<0x128>(a0);           // h^{l-1}_{(j-2)&3}
          const float a3 = dppmov<0x12C>(a0);           // h^{l-1}_{(j-3)&3}
          float acc = fmaf(wih[0], a0, bias);
          acc = fmaf(wih[1], a1, acc);
          float acc2 = wih[2] * a2;
          acc2 = fmaf(wih[3], a3, acc2);
          gx[tc] = acc + acc2;
        }
      }

      // ---- serial step loop: the pipeline's critical path ----
      __builtin_amdgcn_s_setprio(1);
      if (l < NLAYER - 1) {
        float* slotbase = &buf[l][par][0][el][q];
        #pragma unroll
        for (int tc = 0; tc < CHUNK; ++tc)
          lstm_step<true>(gx[tc], whh, k1, k0, hr0, hr1, hr2, hr3, c,
                          slotbase + tc * 64);
      } else {
        #pragma unroll
        for (int tc = 0; tc < CHUNK; ++tc)
          lstm_step<false>(gx[tc], whh, k1, k0, hr0, hr1, hr2, hr3, c,
                           nullptr);
      }
      __builtin_amdgcn_s_setprio(0);

      // ---- final output: hr0 == h at t = T_LEN-1 ----
      if (l == NLAYER - 1 && n == NCHUNK - 1 && gt == 0) out[e * 4 + j] = hr0;
    }
    __syncthreads();   // all 5 waves, every phase (uniform)
  }
}

extern "C" void kernel_launch(void* const* d_in, const int* in_sizes, int n_in,
                              void* d_out, int out_size, void* d_ws, size_t ws_size,
                              hipStream_t stream) {
  const float* x     = (const float*)d_in[0];
  const float* wih0  = (const float*)d_in[1];
  const float* wrest = (const float*)d_in[2];
  const float* whh   = (const float*)d_in[3];
  const float* bih   = (const float*)d_in[4];
  const float* bhh   = (const float*)d_in[5];
  float* out = (float*)d_out;

  dim3 grid(256);            // 1024 elements / 4 per block
  dim3 block(64 * NLAYER);   // 5 waves: one per layer
  lstm_pipe<<<grid, block, 0, stream>>>(x, wih0, wrest, whh, bih, bhh, out);
}

// Round 8
// 287.391 us; speedup vs baseline: 1.2013x; 1.0435x over previous
//
#include <hip/hip_runtime.h>
#include <stdint.h>

// ---------------------------------------------------------------------------
// 5-layer LSTM (H=4, IN=1, B=1024, T=2048) -> final hidden state of top layer.
//
// Layer-pipelined wavefront (5 waves = 5 layers, 4 batch el/block, 256 blocks)
// with PRODUCER-PUSH handoff:
//  - At each step the producer wave already holds the rotated h quadruple
//    hr0..hr3 (= all 4 h values). It computes the NEXT layer's full input
//    contribution gx_next = b_{l+1} + W_ih^{l+1} . h (4 off-chain fmas,
//    next-layer weights preloaded with the same lane->row mapping) and
//    writes THAT to LDS. Consumers read ready-to-use gx: no DPP, no fma,
//    no dependent-latency chain in the phase head.
//  - Handoff layout [boundary][parity][lane][tc] with row stride 33 floats
//    (odd) -> per-step write and chunk reads are 2-way bank aliased (free).
//  - lane q (of 16 per element): hidden j=q>>2, gate gt=q&3, row r=gt*4+j
//    (PyTorch gate order i,f,g,o).
//  - DPP only for cross-lane: quad_perm 0x00/0x55/0xAA/0xFF gathers i/f/g/o;
//    row_ror:4/8/12 gives hr_m = h_{(j-m)&3}; weight columns pre-rotated
//    k=(j-m)&3 to match.
//  - Weights pre-scaled by -log2e (sigmoid rows) / -2log2e (tanh row):
//    activation = 1 v_exp_f32 + 1 v_rcp_f32 + 1 fma;
//    act = fma(k1,R,k0) (tanh = 2*sigmoid(2a)-1); h = fma(2ov,R2,-ov).
//    fma forms have exact limits at E=0/inf -> no clamps needed.
//  - CHUNK=32 steps per phase, ping-pong parity, one __syncthreads/phase.
//  - wave-0 prefetches next x-chunk; s_setprio(1) around the serial loop;
//    top-wave output store hoisted fully out of the phase loop.
// ---------------------------------------------------------------------------

#define T_LEN   2048
#define NLAYER  5
#define CHUNK   32
#define NCHUNK  (T_LEN / CHUNK)        // 64
#define NPHASE  (NCHUNK + NLAYER - 1)  // 68
#define ROWSTR  33                     // odd float stride: conflict-free LDS

template <int CTRL>
__device__ __forceinline__ float dppmov(float x) {
  int v = __builtin_amdgcn_mov_dpp(__float_as_int(x), CTRL, 0xF, 0xF, true);
  return __int_as_float(v);
}

// One LSTM step on the serial critical path. Updates (hr0..hr3, c) in place.
// PUSH: compute next layer's gx from h and publish to the LDS slot.
template <bool PUSH>
__device__ __forceinline__ void lstm_step(
    float gxv, const float* whh, float k1, float k0,
    const float* wnx, float bnx,       // next-layer input weights/bias (PUSH)
    float& hr0, float& hr1, float& hr2, float& hr3, float& c,
    float* __restrict__ slot)          // &buf[l][par][lane][tc] when PUSH
{
  const float LOG2E = 1.4426950408889634f;

  // ---- recurrent pre-activation (tree) ----
  float t01 = fmaf(whh[0], hr0, gxv);
  t01 = fmaf(whh[1], hr1, t01);
  float t23 = whh[2] * hr2;
  t23 = fmaf(whh[3], hr3, t23);
  const float acc = t01 + t23;

  // ---- activation: R = 1/(1+2^acc); act = k1*R + k0 ----
  const float E = __builtin_amdgcn_exp2f(acc);
  const float A = 1.f + E;
  const float R = __builtin_amdgcn_rcpf(A);
  const float act = fmaf(k1, R, k0);

  // ---- gather i,f,g,o of own hidden unit (quad_perm) ----
  const float iv = dppmov<0x00>(act);
  const float fv = dppmov<0x55>(act);
  const float gv = dppmov<0xAA>(act);
  const float ov = dppmov<0xFF>(act);
  const float ov2 = ov + ov;     // off-chain
  const float ovm = -ov;         // off-chain

  // ---- cell + hidden: h = ov * tanh(c) = fma(2ov, R2, -ov) ----
  c = fmaf(fv, c, iv * gv);
  const float ct = c * (-2.0f * LOG2E);
  const float E2 = __builtin_amdgcn_exp2f(ct);
  const float A2 = 1.f + E2;
  const float R2 = __builtin_amdgcn_rcpf(A2);
  const float h  = fmaf(ov2, R2, ovm);

  // ---- rotated h quadruple for next step: hr_m = h_{(j-m)&3} ----
  hr0 = h;
  hr1 = dppmov<0x124>(h);
  hr2 = dppmov<0x128>(h);
  hr3 = dppmov<0x12C>(h);

  // ---- producer-push: next layer's gx (off the critical chain) ----
  if (PUSH) {
    float g = fmaf(wnx[0], hr0, bnx);
    g = fmaf(wnx[1], hr1, g);
    float g2 = wnx[2] * hr2;
    g2 = fmaf(wnx[3], hr3, g2);
    *slot = g + g2;
  }
}

__global__ void __launch_bounds__(64 * NLAYER, 1) lstm_pipe(
    const float* __restrict__ x,         // [1024][2048][1]
    const float* __restrict__ w_ih0,     // [16][1]
    const float* __restrict__ w_ih_rest, // [4][16][4]
    const float* __restrict__ w_hh,      // [5][16][4]
    const float* __restrict__ b_ih,      // [5][16]
    const float* __restrict__ b_hh,      // [5][16]
    float* __restrict__ out)             // [1024][4]
{
  const int tid  = threadIdx.x;
  const int l    = tid >> 6;        // wave id == layer
  const int lane = tid & 63;        // == el*16 + q
  const int q    = lane & 15;
  const int el   = lane >> 4;
  const int e    = blockIdx.x * 4 + el;
  const int gt   = q & 3;           // 0=i 1=f 2=g 3=o
  const int j    = q >> 2;          // hidden unit index
  const int r    = gt * 4 + j;      // row in 4H weight matrices

  const float LOG2E = 1.4426950408889634f;
  const float s  = (gt == 2) ? (-2.0f * LOG2E) : (-LOG2E);
  const float k1 = (gt == 2) ? 2.0f : 1.0f;   // act = fma(k1, R, k0)
  const float k0 = (gt == 2) ? -1.0f : 0.0f;

  // ---- own recurrent weights, columns rotated k=(j-m)&3, pre-scaled ----
  float whh[4];
  #pragma unroll
  for (int m = 0; m < 4; ++m)
    whh[m] = w_hh[l * 64 + r * 4 + ((j - m) & 3)] * s;

  // ---- NEXT layer's input weights + bias (producer-push), same scaling ----
  float wnx[4] = {0.f, 0.f, 0.f, 0.f};
  float bnx = 0.f;
  if (l < NLAYER - 1) {
    #pragma unroll
    for (int m = 0; m < 4; ++m)
      wnx[m] = w_ih_rest[l * 64 + r * 4 + ((j - m) & 3)] * s;   // layer l+1
    bnx = (b_ih[(l + 1) * 16 + r] + b_hh[(l + 1) * 16 + r]) * s;
  }

  // ---- own layer-0 input path ----
  float wx = 0.f, bias0 = 0.f;
  if (l == 0) {
    wx = w_ih0[r] * s;
    bias0 = (b_ih[r] + b_hh[r]) * s;
  }

  // ---- recurrent state: rotated h quadruple + replicated c ----
  float hr0 = 0.f, hr1 = 0.f, hr2 = 0.f, hr3 = 0.f;
  float c = 0.f;

  // handoff: [boundary][parity][lane-row][tc], odd row stride (67.6 KiB)
  __shared__ float buf[NLAYER - 1][2][64][ROWSTR];

  float gx[CHUNK];
  float xcur[CHUNK];   // wave-0 x prefetch buffer (holds chunk n at phase n)

  if (l == 0) {
    #pragma unroll
    for (int tc = 0; tc < CHUNK; ++tc) xcur[tc] = x[e * T_LEN + tc];
  }

  for (int p = 0; p < NPHASE; ++p) {
    const int n = p - l;                 // chunk index for this wave
    if (n >= 0 && n < NCHUNK) {
      const int par = n & 1;

      // ---- phase head: fetch ready-to-use gx for the whole chunk ----
      if (l == 0) {
        #pragma unroll
        for (int tc = 0; tc < CHUNK; ++tc)
          gx[tc] = fmaf(wx, xcur[tc], bias0);
        if (n + 1 < NCHUNK) {            // prefetch next chunk (WAR-ordered)
          #pragma unroll
          for (int tc = 0; tc < CHUNK; ++tc)
            xcur[tc] = x[e * T_LEN + (n + 1) * CHUNK + tc];
        }
      } else {
        const float* row = &buf[l - 1][par][lane][0];
        #pragma unroll
        for (int tc = 0; tc < CHUNK; ++tc) gx[tc] = row[tc];  // 32 indep loads
      }

      // ---- serial step loop: the pipeline's critical path ----
      __builtin_amdgcn_s_setprio(1);
      if (l < NLAYER - 1) {
        float* slot = &buf[l][par][lane][0];
        #pragma unroll
        for (int tc = 0; tc < CHUNK; ++tc)
          lstm_step<true>(gx[tc], whh, k1, k0, wnx, bnx,
                          hr0, hr1, hr2, hr3, c, slot + tc);
      } else {
        #pragma unroll
        for (int tc = 0; tc < CHUNK; ++tc)
          lstm_step<false>(gx[tc], whh, k1, k0, nullptr, 0.f,
                           hr0, hr1, hr2, hr3, c, nullptr);
      }
      __builtin_amdgcn_s_setprio(0);
    }
    __syncthreads();   // all 5 waves, every phase (uniform)
  }

  // ---- final output: top wave's hr0 == h at t = T_LEN-1 ----
  if (l == NLAYER - 1 && gt == 0) out[e * 4 + j] = hr0;
}

extern "C" void kernel_launch(void* const* d_in, const int* in_sizes, int n_in,
                              void* d_out, int out_size, void* d_ws, size_t ws_size,
                              hipStream_t stream) {
  const float* x     = (const float*)d_in[0];
  const float* wih0  = (const float*)d_in[1];
  const float* wrest = (const float*)d_in[2];
  const float* whh   = (const float*)d_in[3];
  const float* bih   = (const float*)d_in[4];
  const float* bhh   = (const float*)d_in[5];
  float* out = (float*)d_out;

  dim3 grid(256);            // 1024 elements / 4 per block
  dim3 block(64 * NLAYER);   // 5 waves: one per layer
  lstm_pipe<<<grid, block, 0, stream>>>(x, wih0, wrest, whh, bih, bhh, out);
}